// Round 2
// baseline (36.401 us; speedup 1.0000x reference)
//
#include <hip/hip_runtime.h>

// STFT→ISTFT roundtrip == elementwise scale (see R0 derivation):
//   out[b,t] = x[b,t] * ws(j)/(ws(j)+1e-6),  j = t mod 512,
//   ws(j) = win[j]^2 + win[j+512]^2.
//
// R2: fully-unrolled 8-deep load batch. n4 = 4,194,304 = 2048 blocks
// * 256 thr * 8 iters exactly. Issue all 8 float4 loads first (128 B
// in flight per thread), then scale+store. Stride (524,288 elems) is
// ≡ 0 mod 512 so the per-thread scale factors are loop-invariant.

__global__ __launch_bounds__(256) void stft_scale_unroll8(
    const float* __restrict__ x,
    const float* __restrict__ win,
    float* __restrict__ out)
{
    const int j = (threadIdx.x << 2) & 511;
    const float4 w0 = *reinterpret_cast<const float4*>(win + j);
    const float4 w1 = *reinterpret_cast<const float4*>(win + j + 512);
    float s0, s1, s2, s3;
    {
        float ws;
        ws = w0.x * w0.x + w1.x * w1.x; s0 = ws / (ws + 1e-6f);
        ws = w0.y * w0.y + w1.y * w1.y; s1 = ws / (ws + 1e-6f);
        ws = w0.z * w0.z + w1.z * w1.z; s2 = ws / (ws + 1e-6f);
        ws = w0.w * w0.w + w1.w * w1.w; s3 = ws / (ws + 1e-6f);
    }

    const float4* __restrict__ xin = reinterpret_cast<const float4*>(x);
    float4* __restrict__ o = reinterpret_cast<float4*>(out);

    const int base   = blockIdx.x * 256 + threadIdx.x;
    const int stride = gridDim.x * 256;          // 524,288

    float4 v[8];
#pragma unroll
    for (int i = 0; i < 8; ++i)
        v[i] = xin[base + i * stride];           // 8 loads in flight

#pragma unroll
    for (int i = 0; i < 8; ++i) {
        float4 t = v[i];
        t.x *= s0; t.y *= s1; t.z *= s2; t.w *= s3;
        o[base + i * stride] = t;
    }
}

// Fallback (general sizes) — same math, grid-stride.
__global__ __launch_bounds__(256) void stft_scale_generic(
    const float* __restrict__ x,
    const float* __restrict__ win,
    float* __restrict__ out,
    int n4)
{
    const int j = (threadIdx.x << 2) & 511;
    const float4 w0 = *reinterpret_cast<const float4*>(win + j);
    const float4 w1 = *reinterpret_cast<const float4*>(win + j + 512);
    float s0, s1, s2, s3;
    {
        float ws;
        ws = w0.x * w0.x + w1.x * w1.x; s0 = ws / (ws + 1e-6f);
        ws = w0.y * w0.y + w1.y * w1.y; s1 = ws / (ws + 1e-6f);
        ws = w0.z * w0.z + w1.z * w1.z; s2 = ws / (ws + 1e-6f);
        ws = w0.w * w0.w + w1.w * w1.w; s3 = ws / (ws + 1e-6f);
    }
    const float4* __restrict__ xin = reinterpret_cast<const float4*>(x);
    float4* __restrict__ o = reinterpret_cast<float4*>(out);
    int idx = blockIdx.x * blockDim.x + threadIdx.x;
    const int stride = gridDim.x * blockDim.x;
    for (; idx < n4; idx += stride) {
        float4 v = xin[idx];
        v.x *= s0; v.y *= s1; v.z *= s2; v.w *= s3;
        o[idx] = v;
    }
}

extern "C" void kernel_launch(void* const* d_in, const int* in_sizes, int n_in,
                              void* d_out, int out_size, void* d_ws, size_t ws_size,
                              hipStream_t stream) {
    const float* x   = (const float*)d_in[0];
    const float* win = (const float*)d_in[3];
    float* out = (float*)d_out;

    const int n4 = out_size >> 2;              // 4,194,304
    if (n4 == 2048 * 256 * 8) {
        stft_scale_unroll8<<<2048, 256, 0, stream>>>(x, win, out);
    } else {
        int blocks = (n4 + 255) / 256;
        if (blocks > 2048) blocks = 2048;
        stft_scale_generic<<<blocks, 256, 0, stream>>>(x, win, out, n4);
    }
}

// Round 3
// 25.139 us; speedup vs baseline: 1.4480x; 1.4480x over previous
//
#include <hip/hip_runtime.h>

// STFT→ISTFT roundtrip == elementwise scale (see R0 derivation):
//   out[b,t] = x[b,t] * ws(j)/(ws(j)+1e-6),  j = t mod 512,
//   ws(j) = win[j]^2 + win[j+512]^2.
//
// R3: 8-deep load batch over a CONTIGUOUS per-block chunk.
// R2's regression: 8 loads/thread at 2 MB strides -> 65k concurrent
// scattered 1KB streams, thrashed DRAM locality. Here each block owns
// a contiguous 32 KB chunk (8 sub-tiles at +256 float4 steps), so the
// in-flight batch is one sequential span; MLP without scatter.
// j-invariance: elem = blk*8192 + tid*4 + i*1024; 8192,1024 ≡ 0 mod 512.

__global__ __launch_bounds__(256) void stft_scale_blk8(
    const float* __restrict__ x,
    const float* __restrict__ win,
    float* __restrict__ out)
{
    const int j = (threadIdx.x << 2) & 511;
    const float4 w0 = *reinterpret_cast<const float4*>(win + j);
    const float4 w1 = *reinterpret_cast<const float4*>(win + j + 512);
    float s0, s1, s2, s3;
    {
        float ws;
        ws = w0.x * w0.x + w1.x * w1.x; s0 = ws / (ws + 1e-6f);
        ws = w0.y * w0.y + w1.y * w1.y; s1 = ws / (ws + 1e-6f);
        ws = w0.z * w0.z + w1.z * w1.z; s2 = ws / (ws + 1e-6f);
        ws = w0.w * w0.w + w1.w * w1.w; s3 = ws / (ws + 1e-6f);
    }

    const float4* __restrict__ xin = reinterpret_cast<const float4*>(x);
    float4* __restrict__ o = reinterpret_cast<float4*>(out);

    // contiguous chunk: block covers float4 indices [blk*2048, blk*2048+2048)
    const int base = blockIdx.x * 2048 + threadIdx.x;

    float4 v[8];
#pragma unroll
    for (int i = 0; i < 8; ++i)
        v[i] = xin[base + i * 256];          // 8 loads, 32 KB sequential span

#pragma unroll
    for (int i = 0; i < 8; ++i) {
        float4 t = v[i];
        t.x *= s0; t.y *= s1; t.z *= s2; t.w *= s3;
        o[base + i * 256] = t;
    }
}

// Fallback for general sizes — R1's proven grid-stride loop.
__global__ __launch_bounds__(256) void stft_scale_generic(
    const float* __restrict__ x,
    const float* __restrict__ win,
    float* __restrict__ out,
    int n4)
{
    const int j = (threadIdx.x << 2) & 511;
    const float4 w0 = *reinterpret_cast<const float4*>(win + j);
    const float4 w1 = *reinterpret_cast<const float4*>(win + j + 512);
    float s0, s1, s2, s3;
    {
        float ws;
        ws = w0.x * w0.x + w1.x * w1.x; s0 = ws / (ws + 1e-6f);
        ws = w0.y * w0.y + w1.y * w1.y; s1 = ws / (ws + 1e-6f);
        ws = w0.z * w0.z + w1.z * w1.z; s2 = ws / (ws + 1e-6f);
        ws = w0.w * w0.w + w1.w * w1.w; s3 = ws / (ws + 1e-6f);
    }
    const float4* __restrict__ xin = reinterpret_cast<const float4*>(x);
    float4* __restrict__ o = reinterpret_cast<float4*>(out);
    int idx = blockIdx.x * blockDim.x + threadIdx.x;
    const int stride = gridDim.x * blockDim.x;
    for (; idx < n4; idx += stride) {
        float4 v = xin[idx];
        v.x *= s0; v.y *= s1; v.z *= s2; v.w *= s3;
        o[idx] = v;
    }
}

extern "C" void kernel_launch(void* const* d_in, const int* in_sizes, int n_in,
                              void* d_out, int out_size, void* d_ws, size_t ws_size,
                              hipStream_t stream) {
    const float* x   = (const float*)d_in[0];
    const float* win = (const float*)d_in[3];
    float* out = (float*)d_out;

    const int n4 = out_size >> 2;              // 4,194,304
    if (n4 == 2048 * 2048) {
        stft_scale_blk8<<<2048, 256, 0, stream>>>(x, win, out);
    } else {
        int blocks = (n4 + 255) / 256;
        if (blocks > 2048) blocks = 2048;
        stft_scale_generic<<<blocks, 256, 0, stream>>>(x, win, out, n4);
    }
}

// Round 5
// 25.090 us; speedup vs baseline: 1.4508x; 1.0020x over previous
//
#include <hip/hip_runtime.h>

// STFT→ISTFT roundtrip == elementwise scale (see R0 derivation):
//   out[b,t] = x[b,t] * ws(j)/(ws(j)+1e-6),  j = t mod 512,
//   ws(j) = win[j]^2 + win[j+512]^2.
//
// R5 = R3 (contiguous per-block 8-deep load batch, 25.1 µs) + NON-TEMPORAL
// stores, using a native clang ext_vector type (HIP's float4 class is
// rejected by __builtin_nontemporal_store). Output is never re-read;
// nt stores avoid evicting the L3-resident input.

typedef float f32x4 __attribute__((ext_vector_type(4)));

__global__ __launch_bounds__(256) void stft_scale_blk8_nt(
    const float* __restrict__ x,
    const float* __restrict__ win,
    float* __restrict__ out)
{
    const int j = (threadIdx.x << 2) & 511;
    const f32x4 w0 = *reinterpret_cast<const f32x4*>(win + j);
    const f32x4 w1 = *reinterpret_cast<const f32x4*>(win + j + 512);
    f32x4 s;
    {
        f32x4 ws = w0 * w0 + w1 * w1;
        s = ws / (ws + 1e-6f);
    }

    const f32x4* __restrict__ xin = reinterpret_cast<const f32x4*>(x);
    f32x4* __restrict__ o = reinterpret_cast<f32x4*>(out);

    const int base = blockIdx.x * 2048 + threadIdx.x;

    f32x4 v[8];
#pragma unroll
    for (int i = 0; i < 8; ++i)
        v[i] = xin[base + i * 256];          // 8 loads, 32 KB sequential span

#pragma unroll
    for (int i = 0; i < 8; ++i)
        __builtin_nontemporal_store(v[i] * s, &o[base + i * 256]);
}

// Fallback for general sizes — R1's proven grid-stride loop.
__global__ __launch_bounds__(256) void stft_scale_generic(
    const float* __restrict__ x,
    const float* __restrict__ win,
    float* __restrict__ out,
    int n4)
{
    const int j = (threadIdx.x << 2) & 511;
    const f32x4 w0 = *reinterpret_cast<const f32x4*>(win + j);
    const f32x4 w1 = *reinterpret_cast<const f32x4*>(win + j + 512);
    f32x4 s;
    {
        f32x4 ws = w0 * w0 + w1 * w1;
        s = ws / (ws + 1e-6f);
    }
    const f32x4* __restrict__ xin = reinterpret_cast<const f32x4*>(x);
    f32x4* __restrict__ o = reinterpret_cast<f32x4*>(out);
    int idx = blockIdx.x * blockDim.x + threadIdx.x;
    const int stride = gridDim.x * blockDim.x;
    for (; idx < n4; idx += stride)
        o[idx] = xin[idx] * s;
}

extern "C" void kernel_launch(void* const* d_in, const int* in_sizes, int n_in,
                              void* d_out, int out_size, void* d_ws, size_t ws_size,
                              hipStream_t stream) {
    const float* x   = (const float*)d_in[0];
    const float* win = (const float*)d_in[3];
    float* out = (float*)d_out;

    const int n4 = out_size >> 2;              // 4,194,304
    if (n4 == 2048 * 2048) {
        stft_scale_blk8_nt<<<2048, 256, 0, stream>>>(x, win, out);
    } else {
        int blocks = (n4 + 255) / 256;
        if (blocks > 2048) blocks = 2048;
        stft_scale_generic<<<blocks, 256, 0, stream>>>(x, win, out, n4);
    }
}